// Round 1
// 293.268 us; speedup vs baseline: 1.0026x; 1.0026x over previous
//
#include <hip/hip_runtime.h>
#include <cstdint>
#include <cstddef>

#define N_ 32
#define H_ 56
#define W_ 56
#define C_ 256
#define HP 58
#define WP 58

typedef int v4i  __attribute__((ext_vector_type(4)));
typedef int v16i __attribute__((ext_vector_type(16)));

// ---------------- kernel 1: weight sign bytes + |k| partial sums ------------
// grid = 36 (idx = tap*4 + quarter), block = 256 (co).
// wi8 layout: [tap][kc(8)][co(256)][32 ci bytes], ci = kc*32 + e (natural order)
// -> bconv B-fragment (col = lane&31 = co, bytes (lane>>5)*16..+15) is one
//    dwordx4, and the whole wave's fragment load is a contiguous 1 KB.
__global__ __launch_bounds__(256) void pack_w(const float* __restrict__ k,
                                              signed char* __restrict__ wi8,
                                              float* __restrict__ palpha) {
    int idx = blockIdx.x;
    int p = idx >> 2, q = idx & 3;       // tap, ci-quarter
    int co = threadIdx.x;
    float s = 0.f;
    #pragma unroll
    for (int half = 0; half < 2; ++half) {
        int kc = q * 2 + half;
        unsigned wrd[8];
        #pragma unroll
        for (int e = 0; e < 8; ++e) {
            unsigned wv = 0;
            #pragma unroll
            for (int j = 0; j < 4; ++j) {
                float v = k[(size_t)(p * 256 + kc * 32 + e * 4 + j) * 256 + co];
                s += fabsf(v);
                wv |= ((v > 0.f) ? 0x01u : 0xFFu) << (8 * j);
            }
            wrd[e] = wv;
        }
        v4i lo = {(int)wrd[0], (int)wrd[1], (int)wrd[2], (int)wrd[3]};
        v4i hi = {(int)wrd[4], (int)wrd[5], (int)wrd[6], (int)wrd[7]};
        size_t base = ((size_t)(p * 8 + kc) * 256 + co) * 2;
        ((v4i*)wi8)[base]     = lo;
        ((v4i*)wi8)[base + 1] = hi;
    }
    palpha[idx * 256 + co] = s;
}

// ---------------- kernel 2: input sign bytes (+-1, pad=-1) + beta -----------
// grid = N_*HP (one padded row), block = 256 = 4 waves. Lane covers channels
// 4*lane..4*lane+3 -> one packed int store per lane (256 B/wave, contiguous).
// Border pixels: bytes 0xFF (-1, since sign(0) = -1 in the ref), beta 0.
__global__ __launch_bounds__(256) void pack_x(const float4* __restrict__ x4,
                                              signed char* __restrict__ xi8,
                                              float* __restrict__ beta) {
    int bi = blockIdx.x;             // n*HP + y (padded row)
    int n = bi / HP, y = bi % HP;
    int wave = threadIdx.x >> 6, lane = threadIdx.x & 63;
    for (int xc = wave; xc < WP; xc += 4) {
        bool inb = (y >= 1 && y <= H_ && xc >= 1 && xc <= W_);
        float4 v = make_float4(0.f, 0.f, 0.f, 0.f);
        if (inb)
            v = x4[(((size_t)n * H_ + (y - 1)) * W_ + (xc - 1)) * 64 + lane];
        unsigned w = ((v.x > 0.f) ? 0x01u : 0xFFu)
                   | (((v.y > 0.f) ? 0x01u : 0xFFu) << 8)
                   | (((v.z > 0.f) ? 0x01u : 0xFFu) << 16)
                   | (((v.w > 0.f) ? 0x01u : 0xFFu) << 24);
        float s = fabsf(v.x) + fabsf(v.y) + fabsf(v.z) + fabsf(v.w);
        #pragma unroll
        for (int m = 32; m >= 1; m >>= 1) s += __shfl_xor(s, m, 64);
        size_t pix = (size_t)bi * WP + xc;
        ((unsigned*)xi8)[pix * 64 + lane] = w;
        if (lane == 0) beta[pix] = s * (1.f / 256.f);
    }
}

// ---------------- kernel 3: implicit-GEMM binary conv via i8 MFMA -----------
// M = 2 output rows (112 pixels, padded to 128), N = 256 couts, K = 2304.
// 8 waves as 2(M) x 4(N); each wave: 2 M-tiles x 2 N-tiles of 32x32, 64 AGPR.
// A staged in LDS with slot ^= (pixel & 15) XOR swizzle (A-frag reads are the
// stride-256B same-bank pattern otherwise). B-frags read straight from global
// (weights = 576 KB, L2-hot in every XCD). No barriers inside the K-loop.
__device__ __forceinline__ void epilogue(const v16i& acc, int mb, int svar,
                                         const float* bS, float alpha, float bv,
                                         int co, size_t obase,
                                         float* __restrict__ out) {
    #pragma unroll
    for (int r = 0; r < 16; ++r) {
        int row = (r & 3) + 8 * (r >> 2) + 4 * svar;   // verified 32x32 C/D map
        int m = mb + row;
        if (m < 112) {
            int hl = (m >= 56);
            int w = m - 56 * hl;
            float val = (float)acc[r] * (bS[m] * alpha) + bv;
            out[obase + ((size_t)hl * W_ + w) * C_ + co] = val;
        }
    }
}

__global__ __launch_bounds__(512, 4) void bconv(
        const signed char* __restrict__ xi8, const float* __restrict__ beta,
        const signed char* __restrict__ wi8, const float* __restrict__ palpha,
        const float* __restrict__ bias, float* __restrict__ out) {
    int bid = blockIdx.x;
    int bi = (bid & 7) * 112 + (bid >> 3);   // XCD swizzle (896 = 8*112, bijective)
    int n = bi / 28;
    int hb = (bi - n * 28) * 2;              // output rows hb, hb+1

    int tid = threadIdx.x;
    int lane = tid & 63, wid = tid >> 6;
    int wm = wid >> 2, wn = wid & 3;
    int l31 = lane & 31, svar = lane >> 5;

    __shared__ __align__(16) signed char xs[4 * WP * 256];   // 59,392 B swizzled
    __shared__ float brow[4 * WP];
    __shared__ float bS[112];

    // stage 4 padded int8 rows; 16B slot sl of pixel pp lands at sl ^ (pp&15)
    {
        const v4i* src = (const v4i*)(xi8 + (size_t)(n * HP + hb) * WP * 256);
        v4i* dst = (v4i*)xs;
        for (int s = tid; s < 4 * WP * 16; s += 512) {
            int pp = s >> 4, sl = s & 15;
            dst[(pp << 4) | (sl ^ (pp & 15))] = src[s];
        }
        const float* bsrc = beta + (size_t)(n * HP + hb) * WP;
        for (int i = tid; i < 4 * WP; i += 512) brow[i] = bsrc[i];
    }
    __syncthreads();

    // 3x3 window sums of beta (the avg_pool) for the 112 output pixels
    if (tid < 112) {
        int r = (tid >= 56);
        int w = tid - 56 * r;
        float s = 0.f;
        #pragma unroll
        for (int rr = 0; rr < 3; ++rr)
            #pragma unroll
            for (int d = 0; d < 3; ++d) s += brow[(r + rr) * WP + w + d];
        bS[tid] = s * (1.f / 9.f);
    }

    // per-lane pixel bases for this wave's two M-tiles (A row = lane&31)
    int m0 = wm * 64 + l31;                       // <= 95, always valid
    int m1 = m0 + 32;
    int m1e = m1 < 112 ? m1 : 111;                // pad lanes clamp, masked at store
    int hl0 = (m0 >= 56), hl1 = (m1e >= 56);
    int pb0 = hl0 * WP + (m0 - 56 * hl0);
    int pb1 = hl1 * WP + (m1e - 56 * hl1);

    int co0 = wn * 64 + l31, co1 = co0 + 32;      // B col = lane&31
    int vb0 = co0 * 2 + svar, vb1 = vb0 + 64;

    v16i acc00 = {0,0,0,0,0,0,0,0,0,0,0,0,0,0,0,0};
    v16i acc01 = acc00, acc10 = acc00, acc11 = acc00;

    const v4i* xsv = (const v4i*)xs;
    const v4i* wv  = (const v4i*)wi8;

    for (int tap = 0; tap < 9; ++tap) {
        int kh = (tap * 11) >> 5;                 // tap/3 for tap in [0,9)
        int kw = tap - kh * 3;
        int p0 = pb0 + kh * WP + kw;
        int p1 = pb1 + kh * WP + kw;
        int a0 = p0 << 4, x0 = p0 & 15;
        int a1 = p1 << 4, x1 = p1 & 15;
        const v4i* bq = wv + (size_t)tap * 8 * 512;
        #pragma unroll
        for (int kc = 0; kc < 8; ++kc) {
            int sl = kc * 2 + svar;
            v4i A0 = xsv[a0 | (sl ^ x0)];
            v4i A1 = xsv[a1 | (sl ^ x1)];
            v4i B0 = bq[vb0];
            v4i B1 = bq[vb1];
            acc00 = __builtin_amdgcn_mfma_i32_32x32x32_i8(A0, B0, acc00, 0, 0, 0);
            acc01 = __builtin_amdgcn_mfma_i32_32x32x32_i8(A0, B1, acc01, 0, 0, 0);
            acc10 = __builtin_amdgcn_mfma_i32_32x32x32_i8(A1, B0, acc10, 0, 0, 0);
            acc11 = __builtin_amdgcn_mfma_i32_32x32x32_i8(A1, B1, acc11, 0, 0, 0);
            bq += 512;
        }
    }

    __syncthreads();   // bS visible to all waves

    float a0s = 0.f, a1s = 0.f;
    for (int i = 0; i < 36; ++i) {
        a0s += palpha[i * 256 + co0];
        a1s += palpha[i * 256 + co1];
    }
    a0s *= (1.f / 2304.f);
    a1s *= (1.f / 2304.f);
    float bv0 = bias[co0], bv1 = bias[co1];

    size_t obase = (size_t)(n * H_ + hb) * W_ * C_;
    epilogue(acc00, wm * 64,      svar, bS, a0s, bv0, co0, obase, out);
    epilogue(acc01, wm * 64,      svar, bS, a1s, bv1, co1, obase, out);
    epilogue(acc10, wm * 64 + 32, svar, bS, a0s, bv0, co0, obase, out);
    epilogue(acc11, wm * 64 + 32, svar, bS, a1s, bv1, co1, obase, out);
}

extern "C" void kernel_launch(void* const* d_in, const int* in_sizes, int n_in,
                              void* d_out, int out_size, void* d_ws, size_t ws_size,
                              hipStream_t stream) {
    const float* x    = (const float*)d_in[0];
    const float* k    = (const float*)d_in[1];
    const float* bias = (const float*)d_in[2];
    float* out = (float*)d_out;

    char* ws = (char*)d_ws;
    signed char* wi8    = (signed char*)(ws);               //    589,824 B
    float*       palpha = (float*)(ws + 589824);            //     36,864 B
    signed char* xi8    = (signed char*)(ws + 626688);      // 27,557,888 B
    float*       beta   = (float*)(ws + 28184576);          //    430,592 B (~28.6 MB)

    pack_w<<<36, 256, 0, stream>>>(k, wi8, palpha);
    pack_x<<<N_ * HP, 256, 0, stream>>>((const float4*)x, xi8, beta);
    bconv<<<896, 512, 0, stream>>>(xi8, beta, wi8, palpha, bias, out);
}

// Round 2
// 260.016 us; speedup vs baseline: 1.1308x; 1.1279x over previous
//
#include <hip/hip_runtime.h>
#include <cstdint>
#include <cstddef>

#define N_ 32
#define H_ 56
#define W_ 56
#define C_ 256
#define HP 58
#define WP 58

typedef int v4i  __attribute__((ext_vector_type(4)));
typedef int v16i __attribute__((ext_vector_type(16)));

// ---------------- kernel 1: weight sign bytes + |k| partial sums ------------
// grid = 36 (idx = tap*4 + quarter), block = 256 (co).
// wi8 layout: [tap][kc(8)][co(256)][32 ci bytes], ci = kc*32 + e (natural order)
// -> bconv B-fragment (col = lane&31 = co, bytes (lane>>5)*16..+15) is one
//    dwordx4, and the whole wave's fragment load is a contiguous 1 KB.
__global__ __launch_bounds__(256) void pack_w(const float* __restrict__ k,
                                              signed char* __restrict__ wi8,
                                              float* __restrict__ palpha) {
    int idx = blockIdx.x;
    int p = idx >> 2, q = idx & 3;       // tap, ci-quarter
    int co = threadIdx.x;
    float s = 0.f;
    #pragma unroll
    for (int half = 0; half < 2; ++half) {
        int kc = q * 2 + half;
        unsigned wrd[8];
        #pragma unroll
        for (int e = 0; e < 8; ++e) {
            unsigned wv = 0;
            #pragma unroll
            for (int j = 0; j < 4; ++j) {
                float v = k[(size_t)(p * 256 + kc * 32 + e * 4 + j) * 256 + co];
                s += fabsf(v);
                wv |= ((v > 0.f) ? 0x01u : 0xFFu) << (8 * j);
            }
            wrd[e] = wv;
        }
        v4i lo = {(int)wrd[0], (int)wrd[1], (int)wrd[2], (int)wrd[3]};
        v4i hi = {(int)wrd[4], (int)wrd[5], (int)wrd[6], (int)wrd[7]};
        size_t base = ((size_t)(p * 8 + kc) * 256 + co) * 2;
        ((v4i*)wi8)[base]     = lo;
        ((v4i*)wi8)[base + 1] = hi;
    }
    palpha[idx * 256 + co] = s;
}

// ---------------- kernel 2: fused pack + implicit-GEMM i8-MFMA conv ---------
// Per block: 2 output rows (M = 112 -> 128), all 256 couts, K = 2304.
// Prologue binarizes the 4 padded f32 input rows straight into swizzled LDS
// (sign(0) = -1 via 0xFF bytes for padding) and computes beta row sums --
// the old pack_x kernel is gone, along with its xi8/beta HBM round trip.
// K-loop: 8 waves as 2(M) x 4(N), each wave 2x2 tiles of 32x32x32 i8 MFMA,
// with explicit 1-step software prefetch of A (LDS) and B (global/L2)
// fragments -- round-1 counters showed VGPR=64 (no compiler pipelining) and
// MfmaUtil 23% ~= the 31 us MFMA floor / 124 us: pure load-latency bound.
__device__ __forceinline__ void epilogue(const v16i& acc, int mb, int svar,
                                         const float* bS, float alpha, float bv,
                                         int co, size_t obase,
                                         float* __restrict__ out) {
    #pragma unroll
    for (int r = 0; r < 16; ++r) {
        int row = (r & 3) + 8 * (r >> 2) + 4 * svar;   // verified 32x32 C/D map
        int m = mb + row;
        if (m < 112) {
            int hl = (m >= 56);
            int w = m - 56 * hl;
            float val = (float)acc[r] * (bS[m] * alpha) + bv;
            out[obase + ((size_t)hl * W_ + w) * C_ + co] = val;
        }
    }
}

__global__ __launch_bounds__(512, 4) void bconv(
        const float4* __restrict__ x4,
        const signed char* __restrict__ wi8, const float* __restrict__ palpha,
        const float* __restrict__ bias, float* __restrict__ out) {
    int bid = blockIdx.x;
    int bi = (bid & 7) * 112 + (bid >> 3);   // XCD swizzle (896 = 8*112, bijective)
    int n = bi / 28;
    int hb = (bi - n * 28) * 2;              // output rows hb, hb+1

    int tid = threadIdx.x;
    int lane = tid & 63, wid = tid >> 6;
    int wm = wid >> 2, wn = wid & 3;
    int l31 = lane & 31, svar = lane >> 5;

    __shared__ __align__(16) signed char xs[4 * WP * 256];   // 59,392 B swizzled
    __shared__ float brow[4 * WP];
    __shared__ float bS[112];

    // ---- fused pack_x: binarize 4 padded rows into swizzled LDS + beta ----
    // 232 pixels, 29 per wave. Lane covers channels 4*lane..4*lane+3; the
    // 4 sign bytes land at slot (lane>>2)^(pp&15), byte (lane&3)*4 -> all 64
    // dwords of the pixel's 256B region distinct (2-way bank alias = free).
    {
        int sl4 = lane >> 2;
        int bo  = (lane & 3) << 2;
        for (int i = 0; i < 29; ++i) {
            int pp = wid + 8 * i;            // 0..231
            int r = pp / WP, xc = pp - r * WP;
            int ypad = hb + r;
            bool inb = (ypad >= 1 && ypad <= H_ && xc >= 1 && xc <= W_);
            float4 v = make_float4(0.f, 0.f, 0.f, 0.f);
            if (inb)
                v = x4[(((size_t)n * H_ + (ypad - 1)) * W_ + (xc - 1)) * 64 + lane];
            unsigned wb = ((v.x > 0.f) ? 0x01u : 0xFFu)
                        | (((v.y > 0.f) ? 0x01u : 0xFFu) << 8)
                        | (((v.z > 0.f) ? 0x01u : 0xFFu) << 16)
                        | (((v.w > 0.f) ? 0x01u : 0xFFu) << 24);
            *(unsigned*)&xs[pp * 256 + ((sl4 ^ (pp & 15)) << 4) + bo] = wb;
            float s = fabsf(v.x) + fabsf(v.y) + fabsf(v.z) + fabsf(v.w);
            #pragma unroll
            for (int m = 32; m >= 1; m >>= 1) s += __shfl_xor(s, m, 64);
            if (lane == 0) brow[pp] = s * (1.f / 256.f);
        }
    }
    __syncthreads();

    // 3x3 window sums of beta (the avg_pool) for the 112 output pixels
    if (tid < 112) {
        int r = (tid >= 56);
        int w = tid - 56 * r;
        float s = 0.f;
        #pragma unroll
        for (int rr = 0; rr < 3; ++rr)
            #pragma unroll
            for (int d = 0; d < 3; ++d) s += brow[(r + rr) * WP + w + d];
        bS[tid] = s * (1.f / 9.f);
    }

    // per-lane pixel bases for this wave's two M-tiles (A row = lane&31)
    int m0 = wm * 64 + l31;                       // <= 95, always valid
    int m1 = m0 + 32;
    int m1e = m1 < 112 ? m1 : 111;                // pad lanes clamp, masked at store
    int hl0 = (m0 >= 56), hl1 = (m1e >= 56);
    int pb0 = hl0 * WP + (m0 - 56 * hl0);
    int pb1 = hl1 * WP + (m1e - 56 * hl1);

    int co0 = wn * 64 + l31, co1 = co0 + 32;      // B col = lane&31
    int vb0 = co0 * 2 + svar, vb1 = vb0 + 64;

    v16i acc00 = {0,0,0,0,0,0,0,0,0,0,0,0,0,0,0,0};
    v16i acc01 = acc00, acc10 = acc00, acc11 = acc00;

    const v4i* xsv = (const v4i*)xs;
    const v4i* wv  = (const v4i*)wi8;

    // ---- K-loop with explicit 1-step prefetch (tap 0, kc 0 preloaded) ----
    int a0c = pb0 << 4, x0c = pb0 & 15;           // tap 0: kh=0, kw=0
    int a1c = pb1 << 4, x1c = pb1 & 15;
    const v4i* bqc = wv;

    v4i A0 = xsv[a0c | (svar ^ x0c)];
    v4i A1 = xsv[a1c | (svar ^ x1c)];
    v4i B0 = bqc[vb0];
    v4i B1 = bqc[vb1];

    for (int tap = 0; tap < 9; ++tap) {
        int tn = (tap < 8) ? tap + 1 : 8;         // clamp: dummy prefetch on last
        int khn = (tn * 11) >> 5, kwn = tn - khn * 3;
        int p0n = pb0 + khn * WP + kwn, p1n = pb1 + khn * WP + kwn;
        int a0n = p0n << 4, x0n = p0n & 15;
        int a1n = p1n << 4, x1n = p1n & 15;
        const v4i* bqn = wv + (size_t)tn * 4096;
        #pragma unroll
        for (int kc = 0; kc < 8; ++kc) {
            // prefetch step (tap, kc+1) -- or (tap+1, 0) at the boundary
            const int nkc = (kc == 7) ? 0 : kc + 1;
            const int sln = nkc * 2 + svar;
            int A0a, A1a;
            const v4i* bq2;
            if (kc == 7) { A0a = a0n | (sln ^ x0n); A1a = a1n | (sln ^ x1n); bq2 = bqn; }
            else         { A0a = a0c | (sln ^ x0c); A1a = a1c | (sln ^ x1c); bq2 = bqc; }
            v4i A0n_ = xsv[A0a];
            v4i A1n_ = xsv[A1a];
            v4i B0n_ = bq2[nkc * 512 + vb0];
            v4i B1n_ = bq2[nkc * 512 + vb1];
            acc00 = __builtin_amdgcn_mfma_i32_32x32x32_i8(A0, B0, acc00, 0, 0, 0);
            acc01 = __builtin_amdgcn_mfma_i32_32x32x32_i8(A0, B1, acc01, 0, 0, 0);
            acc10 = __builtin_amdgcn_mfma_i32_32x32x32_i8(A1, B0, acc10, 0, 0, 0);
            acc11 = __builtin_amdgcn_mfma_i32_32x32x32_i8(A1, B1, acc11, 0, 0, 0);
            A0 = A0n_; A1 = A1n_; B0 = B0n_; B1 = B1n_;
        }
        a0c = a0n; x0c = x0n; a1c = a1n; x1c = x1n; bqc = bqn;
    }

    __syncthreads();   // bS visible to all waves

    float a0s = 0.f, a1s = 0.f;
    for (int i = 0; i < 36; ++i) {
        a0s += palpha[i * 256 + co0];
        a1s += palpha[i * 256 + co1];
    }
    a0s *= (1.f / 2304.f);
    a1s *= (1.f / 2304.f);
    float bv0 = bias[co0], bv1 = bias[co1];

    size_t obase = (size_t)(n * H_ + hb) * W_ * C_;
    epilogue(acc00, wm * 64,      svar, bS, a0s, bv0, co0, obase, out);
    epilogue(acc01, wm * 64,      svar, bS, a1s, bv1, co1, obase, out);
    epilogue(acc10, wm * 64 + 32, svar, bS, a0s, bv0, co0, obase, out);
    epilogue(acc11, wm * 64 + 32, svar, bS, a1s, bv1, co1, obase, out);
}

extern "C" void kernel_launch(void* const* d_in, const int* in_sizes, int n_in,
                              void* d_out, int out_size, void* d_ws, size_t ws_size,
                              hipStream_t stream) {
    const float* x    = (const float*)d_in[0];
    const float* k    = (const float*)d_in[1];
    const float* bias = (const float*)d_in[2];
    float* out = (float*)d_out;

    char* ws = (char*)d_ws;
    signed char* wi8    = (signed char*)(ws);               // 589,824 B
    float*       palpha = (float*)(ws + 589824);            //  36,864 B (total ~627 KB)

    pack_w<<<36, 256, 0, stream>>>(k, wi8, palpha);
    bconv<<<896, 512, 0, stream>>>((const float4*)x, wi8, palpha, bias, out);
}